// Round 14
// baseline (41.041 us; speedup 1.0000x reference)
//
#include <hip/hip_runtime.h>
#include <hip/hip_bf16.h>

#define D_DIM 256
#define K_CODES 1024
#define N_ROWS (32 * 1024)
#define BLOCK_ROWS 32                 // rows per block (2 rg x 16)
#define NBLK (N_ROWS / BLOCK_ROWS)    // 1024 blocks -> 4/CU
#define STEPS 32                      // 16-code fp8 tiles per kg (512 codes)
#define TILE_I64 520                  // 512 frag i64 (4KB) + 8 i64 (en 64B)

typedef __attribute__((ext_vector_type(4))) float f32x4;
typedef __attribute__((ext_vector_type(2))) long i64x2;
typedef long i64;

#define MFMA8 __builtin_amdgcn_mfma_f32_16x16x32_fp8_fp8
#define CVT8 __builtin_amdgcn_cvt_pk_fp8_f32

static __device__ __forceinline__ void gload_lds16(const void* g, void* s) {
    __builtin_amdgcn_global_load_lds(
        (const __attribute__((address_space(1))) void*)g,
        (__attribute__((address_space(3))) void*)s, 16, 0, 0);
}
static __device__ __forceinline__ void gload_lds4(const void* g, void* s) {
    __builtin_amdgcn_global_load_lds(
        (const __attribute__((address_space(1))) void*)g,
        (__attribute__((address_space(3))) void*)s, 4, 0, 0);
}

static __device__ __forceinline__ i64 pack_fp8x8(float4 p, float4 q, float S) {
    int w0 = CVT8(p.x * S, p.y * S, 0, false);
    w0     = CVT8(p.z * S, p.w * S, w0, true);
    int w1 = CVT8(q.x * S, q.y * S, 0, false);
    w1     = CVT8(q.z * S, q.w * S, w1, true);
    return ((i64)(unsigned)w1 << 32) | (unsigned)w0;
}

// ---------------------------------------------------------------- prep
// (a) enorm[k] = ||E[k]||^2 (f32 exact); (b) Eb8 = fp8(-1024*E), B-frag
// order, kk-PAIRED: i64 idx(t16,kk,l) = t16*512 + (kk>>1)*128 + l*2 + (kk&1)
__global__ __launch_bounds__(256) void vq_prep(const float* __restrict__ E,
                                               float* __restrict__ enorm,
                                               i64* __restrict__ Eb8) {
    int wave = threadIdx.x >> 6;
    int lane = threadIdx.x & 63;
    int k = blockIdx.x * 4 + wave;               // [0,1024)
    const float4 v = *reinterpret_cast<const float4*>(E + k * D_DIM + lane * 4);
    float s = v.x * v.x + v.y * v.y + v.z * v.z + v.w * v.w;
    #pragma unroll
    for (int off = 32; off; off >>= 1) s += __shfl_xor(s, off, 64);
    if (lane == 0) enorm[k] = s;

    if (blockIdx.x < 128) {
        int g = blockIdx.x * 256 + threadIdx.x;  // [0, 32768)
        int t = g >> 9;
        int kk = (g >> 6) & 7;
        int l = g & 63;
        int code = t * 16 + (l & 15);
        int d0 = kk * 32 + ((l >> 4) << 3);
        const float* src = E + (size_t)code * D_DIM + d0;
        float4 v0 = *reinterpret_cast<const float4*>(src);
        float4 v1 = *reinterpret_cast<const float4*>(src + 4);
        Eb8[t * 512 + ((kk >> 1) << 7) + l * 2 + (kk & 1)] =
            pack_fp8x8(v0, v1, -1024.0f);
    }
}

// ---------------------------------------------------------------- main
// R13 structure (1024 blocks, 4/CU, 16 waves/CU; wave (kg,rg) = 16 rows x
// 512 codes in 32 fp8 tiles; ring-3 LDS, counted vmcnt(3), 1 barrier/step)
// with two reversions: NO nontemporal stores (writes go through L2 like
// the 6.7 TB/s harness fills) and NO per-step sched_barrier tail fence
// (m141 lesson: don't pin the scheduler; the "memory" clobber on the
// waitcnt already orders the ds_reads).
__global__ __launch_bounds__(256, 4) void vq_main(const float* __restrict__ X,
                                                  const float* __restrict__ E,
                                                  const float* __restrict__ enorm,
                                                  const i64* __restrict__ Eb8,
                                                  float* __restrict__ outq,
                                                  float* __restrict__ lpart) {
    __shared__ i64   Bt[2][3][TILE_I64];   // ~24.4 KB
    __shared__ float mvs[2][BLOCK_ROWS];
    __shared__ int   mis[2][BLOCK_ROWS];
    __shared__ float fxn[BLOCK_ROWS];

    const int tid = threadIdx.x;
    const int w   = tid >> 6;
    const int kg  = w >> 1;       // code half
    const int rg  = w & 1;        // row half
    const int l   = tid & 63;
    const int lr  = l & 15;
    const int lk  = l >> 4;
    const int row0 = blockIdx.x * BLOCK_ROWS;
    const int rowb = row0 + rg * 16;

    // 3 uniform loads/wave/stage: 2 frag KB (rg split) + en (dup by rg)
#define STAGE(T)                                                              \
    do {                                                                      \
        const int t16_ = kg * STEPS + (T);                                    \
        i64* bb = &Bt[kg][(T) % 3][0];                                        \
        _Pragma("unroll")                                                     \
        for (int it = 0; it < 2; ++it) {                                      \
            const int seg = rg * 2 + it;                                      \
            gload_lds16(Eb8 + (size_t)t16_ * 512 + seg * 128 + l * 2,         \
                        bb + seg * 128);                                      \
        }                                                                     \
        if (l < 16) gload_lds4(enorm + t16_ * 16 + l, bb + 512);              \
    } while (0)

    STAGE(0);
    STAGE(1);

    // ---- prologue: 16 rows of X -> fp8 A-frags + f32 row norms
    i64   a[8];
    float xn = 0.0f;
    {
        const float* xp = X + (size_t)(rowb + lr) * D_DIM + lk * 8;
        #pragma unroll
        for (int kk = 0; kk < 8; ++kk) {
            float4 p = *reinterpret_cast<const float4*>(xp + kk * 32);
            float4 q = *reinterpret_cast<const float4*>(xp + kk * 32 + 4);
            xn += p.x * p.x + p.y * p.y + p.z * p.z + p.w * p.w
                + q.x * q.x + q.y * q.y + q.z * q.z + q.w * q.w;
            a[kk] = pack_fp8x8(p, q, 1.0f);
        }
        xn += __shfl_xor(xn, 16, 64);
        xn += __shfl_xor(xn, 32, 64);   // all lanes: norm of row rowb+lr
    }

    float minv[4];
    int   mini[4];
    #pragma unroll
    for (int i = 0; i < 4; ++i) { minv[i] = INFINITY; mini[i] = 0; }

    const float inv = 1.0f / 512.0f;   // undo -1024 scale -> -2 x.e

    #pragma unroll 1
    for (int t = 0; t < STEPS; ++t) {
        if (t < STEPS - 1) { asm volatile("s_waitcnt vmcnt(3)" ::: "memory"); }
        else               { asm volatile("s_waitcnt vmcnt(0)" ::: "memory"); }
        __builtin_amdgcn_s_barrier();   // both rg halves of tile t landed
        __builtin_amdgcn_sched_barrier(0);   // insurance: reads stay below

        const int buf = t % 3;
        i64x2 bp[4];
        #pragma unroll
        for (int p = 0; p < 4; ++p)
            bp[p] = *reinterpret_cast<const i64x2*>(&Bt[kg][buf][p * 128 + l * 2]);
        const float en = reinterpret_cast<const float*>(&Bt[kg][buf][512])[lr];

        if (t < STEPS - 2) STAGE(t + 2);   // into buf (t+2)%3 = (t-1)%3

        f32x4 acc = {0, 0, 0, 0};
        #pragma unroll
        for (int kk = 0; kk < 8; ++kk)
            acc = MFMA8(a[kk], bp[kk >> 1][kk & 1], acc, 0, 0, 0);

        const int idx = (kg * STEPS + t) * 16 + lr;
        #pragma unroll
        for (int i = 0; i < 4; ++i) {
            float s = fmaf(acc[i], inv, en);
            if (s < minv[i]) { minv[i] = s; mini[i] = idx; }
        }
    }
#undef STAGE

    // ---- reduce over the 16 code-lanes (first-min tie-break, butterfly)
    #pragma unroll
    for (int off = 8; off >= 1; off >>= 1) {
        #pragma unroll
        for (int i = 0; i < 4; ++i) {
            float ov = __shfl_xor(minv[i], off, 64);
            int   oi = __shfl_xor(mini[i], off, 64);
            if (ov < minv[i] || (ov == minv[i] && oi < mini[i])) {
                minv[i] = ov; mini[i] = oi;
            }
        }
    }

    // ---- publish: wave covers rows rg*16 + lk*4 + i (lanes lr==0)
    if (lr == 0) {
        #pragma unroll
        for (int i = 0; i < 4; ++i) {
            mvs[kg][rg * 16 + lk * 4 + i] = minv[i];
            mis[kg][rg * 16 + lk * 4 + i] = mini[i];
        }
    }
    if (kg == 0 && l < 16) fxn[rg * 16 + l] = xn;
    __syncthreads();

    // ---- merge kg halves + gather E[idx] -> outq (wave w: rows [w*8,+8))
    #pragma unroll
    for (int rr = 0; rr < 8; ++rr) {
        const int r = w * 8 + rr;
        // kg0 indices < kg1 indices: strict < keeps first-occurrence min
        const int idx = (mvs[1][r] < mvs[0][r]) ? mis[1][r] : mis[0][r];
        const float4 qv = *reinterpret_cast<const float4*>(
            E + (size_t)idx * D_DIM + l * 4);
        *reinterpret_cast<float4*>(outq + (size_t)(row0 + r) * D_DIM + l * 4) = qv;
    }

    // ---- loss partial: wave 0 sums (minval + xnorm) over the 32 rows
    if (w == 0) {
        float v = (l < BLOCK_ROWS) ? (fminf(mvs[0][l], mvs[1][l]) + fxn[l]) : 0.0f;
        #pragma unroll
        for (int off = 32; off; off >>= 1) v += __shfl_xor(v, off, 64);
        if (l == 0) lpart[blockIdx.x] = v;
    }
}

// ---------------------------------------------------------------- finalize
// deterministic fold of 1024 block partials -> vq_loss scalar
__global__ __launch_bounds__(256) void vq_finalize(const float* __restrict__ partials,
                                                   float* __restrict__ out_loss) {
    __shared__ float s[256];
    int t = threadIdx.x;
    s[t] = partials[t] + partials[t + 256] + partials[t + 512] + partials[t + 768];
    __syncthreads();
    #pragma unroll
    for (int off = 128; off; off >>= 1) {
        if (t < off) s[t] += s[t + off];
        __syncthreads();
    }
    if (t == 0)
        out_loss[0] = s[0] * (1.25f / (float)((size_t)N_ROWS * D_DIM));
}

// ---------------------------------------------------------------- launch
extern "C" void kernel_launch(void* const* d_in, const int* in_sizes, int n_in,
                              void* d_out, int out_size, void* d_ws, size_t ws_size,
                              hipStream_t stream) {
    const float* X = (const float*)d_in[0];   // latents  [32768, 256] f32
    const float* E = (const float*)d_in[1];   // codebook [1024, 256]  f32
    float* out = (float*)d_out;               // 8388608 quantized + 1 loss

    float* enorm = (float*)d_ws;                          // 1024 f32
    float* lpart = enorm + K_CODES;                       // 1024 f32
    i64*   Eb8   = (i64*)(lpart + 1024);                  // 256 KB fp8 frags

    vq_prep    <<<256,  256, 0, stream>>>(E, enorm, Eb8);
    vq_main    <<<NBLK, 256, 0, stream>>>(X, E, enorm, Eb8, out, lpart);
    vq_finalize<<<1,    256, 0, stream>>>(lpart, out + (size_t)N_ROWS * D_DIM);
}